// Round 2
// baseline (1118.138 us; speedup 1.0000x reference)
//
#include <hip/hip_runtime.h>
#include <math.h>

#define N_PTS 8192
#define BATCH 4
#define CH 128
#define KNN 20

// ======================================================================
// LAPACK ssyevd emulation for 3x3 symmetric (lower), SINGLE precision,
// matching numpy's float32 eigh path bit-for-bit where decisions matter:
// ssytd2 (exact ssymv/sdot/saxpy/ssyr2 op order) -> ssteqr('I') -> sormtr.
// slartg: LAPACK >= 3.10 convention. All fp32, contraction off.
// ======================================================================

__device__ __forceinline__ float slapy2f(float x, float y) {
#pragma clang fp contract(off)
  float ax = fabsf(x), ay = fabsf(y);
  float w = fmaxf(ax, ay), z = fminf(ax, ay);
  if (z == 0.0f) return w;
  float t = z / w;
  return w * sqrtf(1.0f + t * t);
}

// LAPACK >= 3.10 slartg (moderate-magnitude fast path)
__device__ __forceinline__ void slartgf(float f, float g, float* cs, float* sn, float* r) {
#pragma clang fp contract(off)
  if (g == 0.0f) { *cs = 1.0f; *sn = 0.0f; *r = f; }
  else if (f == 0.0f) { *cs = 0.0f; *sn = copysignf(1.0f, g); *r = fabsf(g); }
  else {
    float f1 = fabsf(f);
    float d = sqrtf(f * f + g * g);
    *cs = f1 / d;
    *r = copysignf(d, f);
    *sn = g / (*r);
  }
}

__device__ void slaev2f(float a, float b, float c, float* rt1, float* rt2,
                        float* cs1, float* sn1) {
#pragma clang fp contract(off)
  float sm = a + c, df = a - c, adf = fabsf(df);
  float tb = b + b, ab = fabsf(tb);
  float acmx, acmn;
  if (fabsf(a) > fabsf(c)) { acmx = a; acmn = c; } else { acmx = c; acmn = a; }
  float rt;
  if (adf > ab)      { float q = ab / adf;  rt = adf * sqrtf(1.0f + q * q); }
  else if (adf < ab) { float q = adf / ab;  rt = ab * sqrtf(1.0f + q * q); }
  else               rt = ab * sqrtf(2.0f);
  int sgn1;
  if (sm < 0.0f)      { *rt1 = 0.5f * (sm - rt); sgn1 = -1; *rt2 = (acmx / *rt1) * acmn - (b / *rt1) * b; }
  else if (sm > 0.0f) { *rt1 = 0.5f * (sm + rt); sgn1 = 1;  *rt2 = (acmx / *rt1) * acmn - (b / *rt1) * b; }
  else                { *rt1 = 0.5f * rt; *rt2 = -0.5f * rt; sgn1 = 1; }
  float cs; int sgn2;
  if (df >= 0.0f) { cs = df + rt; sgn2 = 1; } else { cs = df - rt; sgn2 = -1; }
  float acs = fabsf(cs);
  if (acs > ab) {
    float ct = -tb / cs;
    *sn1 = 1.0f / sqrtf(1.0f + ct * ct);
    *cs1 = ct * (*sn1);
  } else {
    if (ab == 0.0f) { *cs1 = 1.0f; *sn1 = 0.0f; }
    else {
      float tn = -cs / tb;
      *cs1 = 1.0f / sqrtf(1.0f + tn * tn);
      *sn1 = tn * (*cs1);
    }
  }
  if (sgn1 == sgn2) { float tn = *cs1; *cs1 = -(*sn1); *sn1 = tn; }
}

// Full ssyevd path for n=3 (fp32); returns eigenvector of smallest eigenvalue.
__device__ void eigh3_smallest(float a00, float a10, float a20,
                               float a11, float a21, float a22, float evec[3]) {
#pragma clang fp contract(off)
  // ---- ssytd2 (lower): one Householder annihilating a20 ----
  float d[3], e[2], tau = 0.0f, v2 = 0.0f;
  d[0] = a00;
  {
    float xnorm = sqrtf(a20 * a20);   // snrm2(1)
    if (xnorm == 0.0f) {
      tau = 0.0f; v2 = 0.0f;
      e[0] = a10; d[1] = a11; e[1] = a21; d[2] = a22;
    } else {
      float alpha = a10;
      float beta = -copysignf(slapy2f(alpha, xnorm), alpha);
      tau = (beta - alpha) / beta;
      float invs = 1.0f / (alpha - beta);   // sscal: reciprocal then multiply
      v2 = a20 * invs;
      e[0] = beta;
      // ssymv (lower, n=2, alpha=tau, x=(1,v2), beta=0) exact op order:
      //  j=1: y1 = tau*a11; y2 = tau*a21; y1 += tau*(a21*v2)
      //  j=2: y2 += (tau*v2)*a22
      float y0 = tau * a11;
      float y1 = tau * a21;
      y0 = y0 + tau * (a21 * v2);
      y1 = y1 + (tau * v2) * a22;
      // sdot: ((0 + y0*1) + y1*v2)
      float dot = y0 + y1 * v2;
      // alpha2 = (-0.5*tau)*dot ; saxpy: w = y + alpha2*v
      float al = (-0.5f * tau) * dot;
      float w0 = y0 + al;
      float w1 = y1 + al * v2;
      // ssyr2 (lower, alpha=-1) exact op order:
      //  a11 = (a11 + 1*(-w0)) + w0*(-1)
      //  a21 = (a21 + v2*(-w0)) + w1*(-1)
      //  a22 = (a22 + v2*(-w1)) + w1*(-v2)
      a11 = (a11 - w0) - w0;
      a21 = (a21 - v2 * w0) - w1;
      a22 = (a22 - v2 * w1) - w1 * v2;
      d[1] = a11; e[1] = a21; d[2] = a22;
    }
  }

  // ---- ssteqr(compz='I', n=3) ----
  float z[3][3] = {{1.0f,0.0f,0.0f},{0.0f,1.0f,0.0f},{0.0f,0.0f,1.0f}};
  const float eps = 5.9604644775390625e-08f;   // slamch('E') = 2^-24
  const float eps2 = 3.5527136788005009e-15f;  // eps^2 = 2^-48
  const float safmin = 1.1754943508222875e-38f;
  int nmaxit = 90, jtot = 0;
  int l1 = 0;
  int l, m, lend, lsv, lendsv;
  float p, g, r, c, s, f, b_, rt1, rt2, tst;
  float wc[2], wsn[2];

outer_loop:
  if (l1 > 2) goto sorting;
  if (l1 > 0) e[l1 - 1] = 0.0f;
  {
    int mm;
    for (mm = l1; mm <= 1; ++mm) {
      tst = fabsf(e[mm]);
      if (tst == 0.0f) break;
      if (tst <= (sqrtf(fabsf(d[mm])) * sqrtf(fabsf(d[mm + 1]))) * eps) { e[mm] = 0.0f; break; }
    }
    m = (mm > 1) ? 2 : mm;
  }
  l = l1; lsv = l; lend = m; lendsv = lend; l1 = m + 1;
  if (lend == l) goto outer_loop;
  {
    float an = 0.0f;
    for (int i2 = l; i2 <= lend; ++i2) an = fmaxf(an, fabsf(d[i2]));
    for (int i2 = l; i2 < lend; ++i2) an = fmaxf(an, fabsf(e[i2]));
    if (an == 0.0f) goto outer_loop;
  }
  if (fabsf(d[lend]) < fabsf(d[l])) { lend = lsv; l = lendsv; }

  if (lend > l) {
    // ---- QL iteration ----
ql40:
    if (l != lend) {
      for (m = l; m <= lend - 1; ++m) {
        tst = e[m] * e[m];
        if (tst <= (eps2 * fabsf(d[m])) * fabsf(d[m + 1]) + safmin) goto ql60;
      }
    }
    m = lend;
ql60:
    if (m < lend) e[m] = 0.0f;
    p = d[l];
    if (m == l) goto ql80;
    if (m == l + 1) {
      slaev2f(d[l], e[l], d[l + 1], &rt1, &rt2, &c, &s);
      for (int i2 = 0; i2 < 3; ++i2) {
        float temp = z[i2][l + 1];
        z[i2][l + 1] = c * temp - s * z[i2][l];
        z[i2][l]     = s * temp + c * z[i2][l];
      }
      d[l] = rt1; d[l + 1] = rt2; e[l] = 0.0f;
      l += 2;
      if (l <= lend) goto ql40;
      goto done140;
    }
    if (jtot == nmaxit) goto done140;
    jtot++;
    g = (d[l + 1] - p) / (2.0f * e[l]);
    r = slapy2f(g, 1.0f);
    g = d[m] - p + e[l] / (g + copysignf(r, g));
    s = 1.0f; c = 1.0f; p = 0.0f;
    for (int i2 = m - 1; i2 >= l; --i2) {
      f = s * e[i2]; b_ = c * e[i2];
      slartgf(g, f, &c, &s, &r);
      if (i2 != m - 1) e[i2 + 1] = r;
      g = d[i2 + 1] - p;
      r = (d[i2] - g) * s + 2.0f * c * b_;
      p = s * r;
      d[i2 + 1] = g + p;
      g = c * r - b_;
      wc[i2] = c; wsn[i2] = -s;
    }
    for (int j = m - 1; j >= l; --j) {   // slasr 'R','V','B'
      float ct = wc[j], st = wsn[j];
      for (int i2 = 0; i2 < 3; ++i2) {
        float temp = z[i2][j + 1];
        z[i2][j + 1] = ct * temp - st * z[i2][j];
        z[i2][j]     = st * temp + ct * z[i2][j];
      }
    }
    d[l] -= p;
    e[l] = g;
    goto ql40;
ql80:
    d[l] = p;
    l += 1;
    if (l <= lend) goto ql40;
    goto done140;
  } else {
    // ---- QR iteration ----
qr90:
    if (l != lend) {
      for (m = l; m >= lend + 1; --m) {
        tst = e[m - 1] * e[m - 1];
        if (tst <= (eps2 * fabsf(d[m])) * fabsf(d[m - 1]) + safmin) goto qr110;
      }
    }
    m = lend;
qr110:
    if (m > lend) e[m - 1] = 0.0f;
    p = d[l];
    if (m == l) goto qr130;
    if (m == l - 1) {
      slaev2f(d[l - 1], e[l - 1], d[l], &rt1, &rt2, &c, &s);
      for (int i2 = 0; i2 < 3; ++i2) {
        float temp = z[i2][l];
        z[i2][l]     = c * temp - s * z[i2][l - 1];
        z[i2][l - 1] = s * temp + c * z[i2][l - 1];
      }
      d[l - 1] = rt1; d[l] = rt2; e[l - 1] = 0.0f;
      l -= 2;
      if (l >= lend) goto qr90;
      goto done140;
    }
    if (jtot == nmaxit) goto done140;
    jtot++;
    g = (d[l - 1] - p) / (2.0f * e[l - 1]);
    r = slapy2f(g, 1.0f);
    g = d[m] - p + e[l - 1] / (g + copysignf(r, g));
    s = 1.0f; c = 1.0f; p = 0.0f;
    for (int i2 = m; i2 <= l - 1; ++i2) {
      f = s * e[i2]; b_ = c * e[i2];
      slartgf(g, f, &c, &s, &r);
      if (i2 != m) e[i2 - 1] = r;
      g = d[i2] - p;
      r = (d[i2 + 1] - g) * s + 2.0f * c * b_;
      p = s * r;
      d[i2] = g + p;
      g = c * r - b_;
      wc[i2] = c; wsn[i2] = s;
    }
    for (int j = m; j <= l - 1; ++j) {   // slasr 'R','V','F'
      float ct = wc[j], st = wsn[j];
      for (int i2 = 0; i2 < 3; ++i2) {
        float temp = z[i2][j + 1];
        z[i2][j + 1] = ct * temp - st * z[i2][j];
        z[i2][j]     = st * temp + ct * z[i2][j];
      }
    }
    d[l] -= p;
    e[l - 1] = g;
    goto qr90;
qr130:
    d[l] = p;
    l -= 1;
    if (l >= lend) goto qr90;
    goto done140;
  }
done140:
  if (jtot < nmaxit) goto outer_loop;
sorting:
  // selection sort ascending + column swaps (ssteqr tail)
  for (int ii = 1; ii <= 2; ++ii) {
    int i_ = ii - 1, k = i_;
    p = d[i_];
    for (int j = ii; j <= 2; ++j) if (d[j] < p) { k = j; p = d[j]; }
    if (k != i_) {
      d[k] = d[i_]; d[i_] = p;
      for (int i2 = 0; i2 < 3; ++i2) { float tz = z[i2][i_]; z[i2][i_] = z[i2][k]; z[i2][k] = tz; }
    }
  }
  // ---- sormtr: evec = H1 * Z[:,0]  (H2 is identity: tau2=0) ----
  {
    float z10 = z[1][0], z20 = z[2][0];
    float sum = z10 + v2 * z20;
    evec[0] = z[0][0];
    evec[1] = z10 - tau * sum;
    evec[2] = z20 - tau * sum * v2;
  }
}

// ======================================================================
// Kernel 0: prep — pack xyz(+|p|^2) as float4, transpose w1/w2, zero stats
// ======================================================================
__global__ __launch_bounds__(256) void prep_kernel(const float* __restrict__ xyz,
                                                   const float* __restrict__ w1,
                                                   const float* __restrict__ w2,
                                                   float4* __restrict__ xyz4,
                                                   float* __restrict__ w1t,
                                                   float* __restrict__ w2t,
                                                   float* __restrict__ stats) {
  int idx = blockIdx.x * 256 + threadIdx.x;
  if (idx < BATCH * N_PTS) {
    float x = xyz[idx * 3], y = xyz[idx * 3 + 1], zz = xyz[idx * 3 + 2];
    float sq = fmaf(zz, zz, fmaf(y, y, x * x));
    xyz4[idx] = make_float4(x, y, zz, sq);
  }
  if (idx < 132 * CH) {  // w1t[c][o], rows 0..130 from w1, row 131 = 0
    int cc = idx >> 7, o = idx & 127;
    w1t[idx] = (cc < 131) ? w1[o * 131 + cc] : 0.0f;
  }
  if (idx < CH * CH) {   // w2t[c][o]
    int cc = idx >> 7, o = idx & 127;
    w2t[idx] = w2[o * CH + cc];
  }
  if (idx < 256) stats[idx] = 0.0f;
}

// ======================================================================
// Kernel 1: brute-force exact 20-NN + covariance + eigh -> normals
// 256 threads / 128 queries per block; waves 0-1 scan [0,4096),
// waves 2-3 scan [4096,8192); merge sorted top-20 lists via LDS.
// ======================================================================
__global__ __launch_bounds__(256) void knn_normals_kernel(const float4* __restrict__ xyz4,
                                                          float4* __restrict__ nrm4) {
  __shared__ float sd[256 * KNN];
  __shared__ int   si[256 * KNN];
  const int t = threadIdx.x;
  const int b = blockIdx.x >> 6;            // 64 blocks per batch
  const int base = (blockIdx.x & 63) << 7;  // 128 queries per block
  const int q = base + (t & 127);
  const float4* __restrict__ xb = xyz4 + b * N_PTS;
  const float4 qv = xb[q];

  float bd[KNN]; int bi[KNN];
#pragma unroll
  for (int j = 0; j < KNN; ++j) { bd[j] = INFINITY; bi[j] = 0x7fffffff; }

  const int m0 = __builtin_amdgcn_readfirstlane((t >> 7) * (N_PTS / 2));
  const int m1 = m0 + N_PTS / 2;
  for (int m = m0; m < m1; ++m) {
    const float4 cv = xb[m];  // uniform address -> scalar load
    float dot = fmaf(qv.x, cv.x, fmaf(qv.y, cv.y, qv.z * cv.z));
    float dist = fmaf(-2.0f, dot, qv.w + cv.w);
    if (dist < bd[KNN - 1]) {                // strict < : ties keep lower index
      bd[KNN - 1] = dist; bi[KNN - 1] = m;
#pragma unroll
      for (int j = KNN - 1; j > 0; --j) {
        float a = bd[j - 1]; float bb = bd[j];
        int ai = bi[j - 1]; int bbi = bi[j];
        bool sw = bb < a;
        bd[j - 1] = sw ? bb : a;  bd[j] = sw ? a : bb;
        bi[j - 1] = sw ? bbi : ai; bi[j] = sw ? ai : bbi;
      }
    }
  }

#pragma unroll
  for (int j = 0; j < KNN; ++j) { sd[t * KNN + j] = bd[j]; si[t * KNN + j] = bi[j]; }
  __syncthreads();

  if (t < 128) {
    int pa = t * KNN, pb = (t + 128) * KNN;
    const int ea = pa + KNN, eb = pb + KNN;
    int mi[KNN];
#pragma unroll
    for (int j = 0; j < KNN; ++j) {
      float da = (pa < ea) ? sd[pa] : INFINITY;
      float db = (pb < eb) ? sd[pb] : INFINITY;
      bool takeA = (da <= db);   // ties -> list A (lower indices)
      mi[j] = takeA ? si[pa] : si[pb];
      pa += takeA ? 1 : 0;
      pb += takeA ? 0 : 1;
    }
    // covariance: fp32, sequential over k ascending (matches np.einsum), no FMA
    float c00, c01, c02, c11, c12, c22;
    {
#pragma clang fp contract(off)
      c00 = 0.f; c01 = 0.f; c02 = 0.f; c11 = 0.f; c12 = 0.f; c22 = 0.f;
      for (int j = 0; j < KNN; ++j) {
        float4 pv = xb[mi[j]];
        float dx = pv.x - qv.x, dy = pv.y - qv.y, dz = pv.z - qv.z;
        c00 = c00 + dx * dx; c01 = c01 + dx * dy; c02 = c02 + dx * dz;
        c11 = c11 + dy * dy; c12 = c12 + dy * dz; c22 = c22 + dz * dz;
      }
    }
    float ev[3];
    eigh3_smallest(c00, c01, c02, c11, c12, c22, ev);
    nrm4[b * N_PTS + q] = make_float4(ev[0], ev[1], ev[2], 0.0f);
  }
}

// ======================================================================
// Kernel 2: GEMM1 (w1 @ [x; normals] + b1) -> per-channel sum/sumsq
// ======================================================================
__global__ __launch_bounds__(256) void gemm1_stats_kernel(const float* __restrict__ x,
                                                          const float4* __restrict__ nrm4,
                                                          const float* __restrict__ w1t,
                                                          const float* __restrict__ b1,
                                                          float* __restrict__ sums,
                                                          float* __restrict__ sumsq) {
  __shared__ float lds[64 * 134];
  const int t = threadIdx.x;
  const int b = blockIdx.x >> 7;             // 128 blocks per batch
  const int n0 = (blockIdx.x & 127) << 6;    // 64 points per block
  for (int idx = t; idx < CH * 64; idx += 256) {
    int cc = idx >> 6, nl = idx & 63;
    lds[nl * 134 + cc] = x[((size_t)(b * CH + cc)) * N_PTS + n0 + nl];
  }
  if (t < 64) {
    float4 nv = nrm4[b * N_PTS + n0 + t];
    lds[t * 134 + 128] = nv.x; lds[t * 134 + 129] = nv.y;
    lds[t * 134 + 130] = nv.z; lds[t * 134 + 131] = 0.0f;
  }
  __syncthreads();

  const int og = __builtin_amdgcn_readfirstlane(t >> 6);
  const int nl = t & 63;
  float acc[32];
#pragma unroll
  for (int k = 0; k < 32; ++k) acc[k] = b1[og * 32 + k];
  for (int c2 = 0; c2 < 66; ++c2) {
    float2 xv = *(const float2*)&lds[nl * 134 + 2 * c2];
    const float* wr0 = w1t + (2 * c2) * CH + og * 32;
    const float* wr1 = wr0 + CH;
#pragma unroll
    for (int k = 0; k < 32; ++k) acc[k] = fmaf(wr0[k], xv.x, acc[k]);
#pragma unroll
    for (int k = 0; k < 32; ++k) acc[k] = fmaf(wr1[k], xv.y, acc[k]);
  }
  __syncthreads();
#pragma unroll
  for (int k2 = 0; k2 < 16; ++k2)
    *(float2*)&lds[nl * 134 + og * 32 + 2 * k2] = make_float2(acc[2 * k2], acc[2 * k2 + 1]);
  __syncthreads();
  {
    int cc = t & 127, hf = t >> 7;
    float sm = 0.f, sq = 0.f;
    for (int rr = hf * 32; rr < hf * 32 + 32; ++rr) {
      float v = lds[rr * 134 + cc];
      sm += v; sq = fmaf(v, v, sq);
    }
    atomicAdd(&sums[cc], sm);
    atomicAdd(&sumsq[cc], sq);
  }
}

// ======================================================================
// Kernel 3: finalize BN scale/shift (double precision)
// ======================================================================
__global__ void bn_finalize_kernel(const float* __restrict__ sums, const float* __restrict__ sumsq,
                                   const float* __restrict__ gamma, const float* __restrict__ beta,
                                   float* __restrict__ scale, float* __restrict__ shift) {
  int c = threadIdx.x;
  if (c < CH) {
    const double cnt = (double)(BATCH * N_PTS);
    double mean = (double)sums[c] / cnt;
    double var = (double)sumsq[c] / cnt - mean * mean;
    double inv = 1.0 / sqrt(var + 1e-5);
    double sc = (double)gamma[c] * inv;
    scale[c] = (float)sc;
    shift[c] = (float)((double)beta[c] - mean * sc);
  }
}

// ======================================================================
// Kernel 4: fused GEMM1 (recompute) + BN + ReLU + GEMM2 -> out
// ======================================================================
__global__ __launch_bounds__(256) void fused_out_kernel(const float* __restrict__ x,
                                                        const float4* __restrict__ nrm4,
                                                        const float* __restrict__ w1t,
                                                        const float* __restrict__ b1,
                                                        const float* __restrict__ w2t,
                                                        const float* __restrict__ b2,
                                                        const float* __restrict__ scale,
                                                        const float* __restrict__ shift,
                                                        float* __restrict__ out) {
  __shared__ float lds[64 * 134];
  const int t = threadIdx.x;
  const int b = blockIdx.x >> 7;
  const int n0 = (blockIdx.x & 127) << 6;
  for (int idx = t; idx < CH * 64; idx += 256) {
    int cc = idx >> 6, nl = idx & 63;
    lds[nl * 134 + cc] = x[((size_t)(b * CH + cc)) * N_PTS + n0 + nl];
  }
  if (t < 64) {
    float4 nv = nrm4[b * N_PTS + n0 + t];
    lds[t * 134 + 128] = nv.x; lds[t * 134 + 129] = nv.y;
    lds[t * 134 + 130] = nv.z; lds[t * 134 + 131] = 0.0f;
  }
  __syncthreads();

  const int og = __builtin_amdgcn_readfirstlane(t >> 6);
  const int nl = t & 63;
  float acc[32];
#pragma unroll
  for (int k = 0; k < 32; ++k) acc[k] = b1[og * 32 + k];
  for (int c2 = 0; c2 < 66; ++c2) {
    float2 xv = *(const float2*)&lds[nl * 134 + 2 * c2];
    const float* wr0 = w1t + (2 * c2) * CH + og * 32;
    const float* wr1 = wr0 + CH;
#pragma unroll
    for (int k = 0; k < 32; ++k) acc[k] = fmaf(wr0[k], xv.x, acc[k]);
#pragma unroll
    for (int k = 0; k < 32; ++k) acc[k] = fmaf(wr1[k], xv.y, acc[k]);
  }
  // BN + ReLU
#pragma unroll
  for (int k = 0; k < 32; ++k) {
    float sc = scale[og * 32 + k], sh = shift[og * 32 + k];
    acc[k] = fmaxf(fmaf(acc[k], sc, sh), 0.0f);
  }
  __syncthreads();
#pragma unroll
  for (int k2 = 0; k2 < 16; ++k2)
    *(float2*)&lds[nl * 134 + og * 32 + 2 * k2] = make_float2(acc[2 * k2], acc[2 * k2 + 1]);
  __syncthreads();

  float acc2[32];
#pragma unroll
  for (int k = 0; k < 32; ++k) acc2[k] = b2[og * 32 + k];
  for (int c2 = 0; c2 < 64; ++c2) {
    float2 hv = *(const float2*)&lds[nl * 134 + 2 * c2];
    const float* wr0 = w2t + (2 * c2) * CH + og * 32;
    const float* wr1 = wr0 + CH;
#pragma unroll
    for (int k = 0; k < 32; ++k) acc2[k] = fmaf(wr0[k], hv.x, acc2[k]);
#pragma unroll
    for (int k = 0; k < 32; ++k) acc2[k] = fmaf(wr1[k], hv.y, acc2[k]);
  }
#pragma unroll
  for (int k = 0; k < 32; ++k) {
    int o = og * 32 + k;
    out[((size_t)(b * CH + o)) * N_PTS + n0 + nl] = acc2[k];
  }
}

// ======================================================================
extern "C" void kernel_launch(void* const* d_in, const int* in_sizes, int n_in,
                              void* d_out, int out_size, void* d_ws, size_t ws_size,
                              hipStream_t stream) {
  const float* x     = (const float*)d_in[0];
  const float* xyz   = (const float*)d_in[1];
  const float* w1    = (const float*)d_in[2];
  const float* b1    = (const float*)d_in[3];
  const float* gamma = (const float*)d_in[4];
  const float* beta  = (const float*)d_in[5];
  const float* w2    = (const float*)d_in[6];
  const float* b2    = (const float*)d_in[7];
  float* out = (float*)d_out;

  float* W = (float*)d_ws;
  float4* xyz4 = (float4*)W;                         // 131072 floats
  float4* nrm4 = (float4*)(W + 131072);              // 131072 floats
  float* w1t   = W + 262144;                         // 132*128 = 16896
  float* w2t   = W + 279040;                         // 128*128 = 16384
  float* stats = W + 295424;                         // sums[128] | sumsq[128]
  float* scale = W + 295680;                         // 128
  float* shift = W + 295808;                         // 128

  prep_kernel<<<128, 256, 0, stream>>>(xyz, w1, w2, xyz4, w1t, w2t, stats);
  knn_normals_kernel<<<BATCH * N_PTS / 128, 256, 0, stream>>>(xyz4, nrm4);
  gemm1_stats_kernel<<<BATCH * N_PTS / 64, 256, 0, stream>>>(x, nrm4, w1t, b1, stats, stats + 128);
  bn_finalize_kernel<<<1, 128, 0, stream>>>(stats, stats + 128, gamma, beta, scale, shift);
  fused_out_kernel<<<BATCH * N_PTS / 64, 256, 0, stream>>>(x, nrm4, w1t, b1, w2t, b2, scale, shift, out);
}

// Round 3
// 467.964 us; speedup vs baseline: 2.3894x; 2.3894x over previous
//
#include <hip/hip_runtime.h>
#include <math.h>

#define N_PTS 8192
#define BATCH 4
#define CH 128
#define KNN 20
#define CAP 64

// ======================================================================
// LAPACK ssyevd emulation for 3x3 symmetric (lower), SINGLE precision,
// matching numpy's float32 eigh path bit-for-bit where decisions matter:
// ssytd2 (exact ssymv/sdot/saxpy/ssyr2 op order) -> ssteqr('I') -> sormtr.
// slartg: LAPACK >= 3.10 convention. All fp32, contraction off.
// (verified passing in round 2 — do not perturb numerics)
// ======================================================================

__device__ __forceinline__ float slapy2f(float x, float y) {
#pragma clang fp contract(off)
  float ax = fabsf(x), ay = fabsf(y);
  float w = fmaxf(ax, ay), z = fminf(ax, ay);
  if (z == 0.0f) return w;
  float t = z / w;
  return w * sqrtf(1.0f + t * t);
}

__device__ __forceinline__ void slartgf(float f, float g, float* cs, float* sn, float* r) {
#pragma clang fp contract(off)
  if (g == 0.0f) { *cs = 1.0f; *sn = 0.0f; *r = f; }
  else if (f == 0.0f) { *cs = 0.0f; *sn = copysignf(1.0f, g); *r = fabsf(g); }
  else {
    float f1 = fabsf(f);
    float d = sqrtf(f * f + g * g);
    *cs = f1 / d;
    *r = copysignf(d, f);
    *sn = g / (*r);
  }
}

__device__ void slaev2f(float a, float b, float c, float* rt1, float* rt2,
                        float* cs1, float* sn1) {
#pragma clang fp contract(off)
  float sm = a + c, df = a - c, adf = fabsf(df);
  float tb = b + b, ab = fabsf(tb);
  float acmx, acmn;
  if (fabsf(a) > fabsf(c)) { acmx = a; acmn = c; } else { acmx = c; acmn = a; }
  float rt;
  if (adf > ab)      { float q = ab / adf;  rt = adf * sqrtf(1.0f + q * q); }
  else if (adf < ab) { float q = adf / ab;  rt = ab * sqrtf(1.0f + q * q); }
  else               rt = ab * sqrtf(2.0f);
  int sgn1;
  if (sm < 0.0f)      { *rt1 = 0.5f * (sm - rt); sgn1 = -1; *rt2 = (acmx / *rt1) * acmn - (b / *rt1) * b; }
  else if (sm > 0.0f) { *rt1 = 0.5f * (sm + rt); sgn1 = 1;  *rt2 = (acmx / *rt1) * acmn - (b / *rt1) * b; }
  else                { *rt1 = 0.5f * rt; *rt2 = -0.5f * rt; sgn1 = 1; }
  float cs; int sgn2;
  if (df >= 0.0f) { cs = df + rt; sgn2 = 1; } else { cs = df - rt; sgn2 = -1; }
  float acs = fabsf(cs);
  if (acs > ab) {
    float ct = -tb / cs;
    *sn1 = 1.0f / sqrtf(1.0f + ct * ct);
    *cs1 = ct * (*sn1);
  } else {
    if (ab == 0.0f) { *cs1 = 1.0f; *sn1 = 0.0f; }
    else {
      float tn = -cs / tb;
      *cs1 = 1.0f / sqrtf(1.0f + tn * tn);
      *sn1 = tn * (*cs1);
    }
  }
  if (sgn1 == sgn2) { float tn = *cs1; *cs1 = -(*sn1); *sn1 = tn; }
}

__device__ void eigh3_smallest(float a00, float a10, float a20,
                               float a11, float a21, float a22, float evec[3]) {
#pragma clang fp contract(off)
  float d[3], e[2], tau = 0.0f, v2 = 0.0f;
  d[0] = a00;
  {
    float xnorm = sqrtf(a20 * a20);   // snrm2(1)
    if (xnorm == 0.0f) {
      tau = 0.0f; v2 = 0.0f;
      e[0] = a10; d[1] = a11; e[1] = a21; d[2] = a22;
    } else {
      float alpha = a10;
      float beta = -copysignf(slapy2f(alpha, xnorm), alpha);
      tau = (beta - alpha) / beta;
      float invs = 1.0f / (alpha - beta);
      v2 = a20 * invs;
      e[0] = beta;
      float y0 = tau * a11;
      float y1 = tau * a21;
      y0 = y0 + tau * (a21 * v2);
      y1 = y1 + (tau * v2) * a22;
      float dot = y0 + y1 * v2;
      float al = (-0.5f * tau) * dot;
      float w0 = y0 + al;
      float w1 = y1 + al * v2;
      a11 = (a11 - w0) - w0;
      a21 = (a21 - v2 * w0) - w1;
      a22 = (a22 - v2 * w1) - w1 * v2;
      d[1] = a11; e[1] = a21; d[2] = a22;
    }
  }

  float z[3][3] = {{1.0f,0.0f,0.0f},{0.0f,1.0f,0.0f},{0.0f,0.0f,1.0f}};
  const float eps = 5.9604644775390625e-08f;
  const float eps2 = 3.5527136788005009e-15f;
  const float safmin = 1.1754943508222875e-38f;
  int nmaxit = 90, jtot = 0;
  int l1 = 0;
  int l, m, lend, lsv, lendsv;
  float p, g, r, c, s, f, b_, rt1, rt2, tst;
  float wc[2], wsn[2];

outer_loop:
  if (l1 > 2) goto sorting;
  if (l1 > 0) e[l1 - 1] = 0.0f;
  {
    int mm;
    for (mm = l1; mm <= 1; ++mm) {
      tst = fabsf(e[mm]);
      if (tst == 0.0f) break;
      if (tst <= (sqrtf(fabsf(d[mm])) * sqrtf(fabsf(d[mm + 1]))) * eps) { e[mm] = 0.0f; break; }
    }
    m = (mm > 1) ? 2 : mm;
  }
  l = l1; lsv = l; lend = m; lendsv = lend; l1 = m + 1;
  if (lend == l) goto outer_loop;
  {
    float an = 0.0f;
    for (int i2 = l; i2 <= lend; ++i2) an = fmaxf(an, fabsf(d[i2]));
    for (int i2 = l; i2 < lend; ++i2) an = fmaxf(an, fabsf(e[i2]));
    if (an == 0.0f) goto outer_loop;
  }
  if (fabsf(d[lend]) < fabsf(d[l])) { lend = lsv; l = lendsv; }

  if (lend > l) {
ql40:
    if (l != lend) {
      for (m = l; m <= lend - 1; ++m) {
        tst = e[m] * e[m];
        if (tst <= (eps2 * fabsf(d[m])) * fabsf(d[m + 1]) + safmin) goto ql60;
      }
    }
    m = lend;
ql60:
    if (m < lend) e[m] = 0.0f;
    p = d[l];
    if (m == l) goto ql80;
    if (m == l + 1) {
      slaev2f(d[l], e[l], d[l + 1], &rt1, &rt2, &c, &s);
      for (int i2 = 0; i2 < 3; ++i2) {
        float temp = z[i2][l + 1];
        z[i2][l + 1] = c * temp - s * z[i2][l];
        z[i2][l]     = s * temp + c * z[i2][l];
      }
      d[l] = rt1; d[l + 1] = rt2; e[l] = 0.0f;
      l += 2;
      if (l <= lend) goto ql40;
      goto done140;
    }
    if (jtot == nmaxit) goto done140;
    jtot++;
    g = (d[l + 1] - p) / (2.0f * e[l]);
    r = slapy2f(g, 1.0f);
    g = d[m] - p + e[l] / (g + copysignf(r, g));
    s = 1.0f; c = 1.0f; p = 0.0f;
    for (int i2 = m - 1; i2 >= l; --i2) {
      f = s * e[i2]; b_ = c * e[i2];
      slartgf(g, f, &c, &s, &r);
      if (i2 != m - 1) e[i2 + 1] = r;
      g = d[i2 + 1] - p;
      r = (d[i2] - g) * s + 2.0f * c * b_;
      p = s * r;
      d[i2 + 1] = g + p;
      g = c * r - b_;
      wc[i2] = c; wsn[i2] = -s;
    }
    for (int j = m - 1; j >= l; --j) {
      float ct = wc[j], st = wsn[j];
      for (int i2 = 0; i2 < 3; ++i2) {
        float temp = z[i2][j + 1];
        z[i2][j + 1] = ct * temp - st * z[i2][j];
        z[i2][j]     = st * temp + ct * z[i2][j];
      }
    }
    d[l] -= p;
    e[l] = g;
    goto ql40;
ql80:
    d[l] = p;
    l += 1;
    if (l <= lend) goto ql40;
    goto done140;
  } else {
qr90:
    if (l != lend) {
      for (m = l; m >= lend + 1; --m) {
        tst = e[m - 1] * e[m - 1];
        if (tst <= (eps2 * fabsf(d[m])) * fabsf(d[m - 1]) + safmin) goto qr110;
      }
    }
    m = lend;
qr110:
    if (m > lend) e[m - 1] = 0.0f;
    p = d[l];
    if (m == l) goto qr130;
    if (m == l - 1) {
      slaev2f(d[l - 1], e[l - 1], d[l], &rt1, &rt2, &c, &s);
      for (int i2 = 0; i2 < 3; ++i2) {
        float temp = z[i2][l];
        z[i2][l]     = c * temp - s * z[i2][l - 1];
        z[i2][l - 1] = s * temp + c * z[i2][l - 1];
      }
      d[l - 1] = rt1; d[l] = rt2; e[l - 1] = 0.0f;
      l -= 2;
      if (l >= lend) goto qr90;
      goto done140;
    }
    if (jtot == nmaxit) goto done140;
    jtot++;
    g = (d[l - 1] - p) / (2.0f * e[l - 1]);
    r = slapy2f(g, 1.0f);
    g = d[m] - p + e[l - 1] / (g + copysignf(r, g));
    s = 1.0f; c = 1.0f; p = 0.0f;
    for (int i2 = m; i2 <= l - 1; ++i2) {
      f = s * e[i2]; b_ = c * e[i2];
      slartgf(g, f, &c, &s, &r);
      if (i2 != m) e[i2 - 1] = r;
      g = d[i2] - p;
      r = (d[i2 + 1] - g) * s + 2.0f * c * b_;
      p = s * r;
      d[i2] = g + p;
      g = c * r - b_;
      wc[i2] = c; wsn[i2] = s;
    }
    for (int j = m; j <= l - 1; ++j) {
      float ct = wc[j], st = wsn[j];
      for (int i2 = 0; i2 < 3; ++i2) {
        float temp = z[i2][j + 1];
        z[i2][j + 1] = ct * temp - st * z[i2][j];
        z[i2][j]     = st * temp + ct * z[i2][j];
      }
    }
    d[l] -= p;
    e[l - 1] = g;
    goto qr90;
qr130:
    d[l] = p;
    l -= 1;
    if (l >= lend) goto qr90;
    goto done140;
  }
done140:
  if (jtot < nmaxit) goto outer_loop;
sorting:
  for (int ii = 1; ii <= 2; ++ii) {
    int i_ = ii - 1, k = i_;
    p = d[i_];
    for (int j = ii; j <= 2; ++j) if (d[j] < p) { k = j; p = d[j]; }
    if (k != i_) {
      d[k] = d[i_]; d[i_] = p;
      for (int i2 = 0; i2 < 3; ++i2) { float tz = z[i2][i_]; z[i2][i_] = z[i2][k]; z[i2][k] = tz; }
    }
  }
  {
    float z10 = z[1][0], z20 = z[2][0];
    float sum = z10 + v2 * z20;
    evec[0] = z[0][0];
    evec[1] = z10 - tau * sum;
    evec[2] = z20 - tau * sum * v2;
  }
}

// ======================================================================
// Kernel 0: prep — pack xyz(+|p|^2) as float4, transpose w1/w2, zero stats
// ======================================================================
__global__ __launch_bounds__(256) void prep_kernel(const float* __restrict__ xyz,
                                                   const float* __restrict__ w1,
                                                   const float* __restrict__ w2,
                                                   float4* __restrict__ xyz4,
                                                   float* __restrict__ w1t,
                                                   float* __restrict__ w2t,
                                                   float* __restrict__ stats) {
  int idx = blockIdx.x * 256 + threadIdx.x;
  if (idx < BATCH * N_PTS) {
    float x = xyz[idx * 3], y = xyz[idx * 3 + 1], zz = xyz[idx * 3 + 2];
    float sq = fmaf(zz, zz, fmaf(y, y, x * x));
    xyz4[idx] = make_float4(x, y, zz, sq);
  }
  if (idx < 132 * CH) {
    int cc = idx >> 7, o = idx & 127;
    w1t[idx] = (cc < 131) ? w1[o * 131 + cc] : 0.0f;
  }
  if (idx < CH * CH) {
    int cc = idx >> 7, o = idx & 127;
    w2t[idx] = w2[o * CH + cc];
  }
  if (idx < 256) stats[idx] = 0.0f;
}

// ======================================================================
// distance identical to round-2 (bit-deterministic, used by all scans)
// ======================================================================
__device__ __forceinline__ float qdist(const float4 qv, const float4 cv) {
  float dot = fmaf(qv.x, cv.x, fmaf(qv.y, cv.y, qv.z * cv.z));
  return fmaf(-2.0f, dot, qv.w + cv.w);
}

__device__ __forceinline__ unsigned long long packdi(float dist, int idx) {
  unsigned int du = __float_as_uint(dist);
  unsigned int s = (du & 0x80000000u) ? ~du : (du | 0x80000000u);  // total order
  return ((unsigned long long)s << 32) | (unsigned int)idx;
}

// ======================================================================
// Kernel 1: exact 20-NN via histogram select (no streaming insertion).
// Block: 512 threads = 8 waves; 64 queries (lane=query); wave w scans
// candidate chunk [1024w, 1024w+1024) with wave-uniform scalar loads.
//  P1: per-lane 20 stripe-minima -> T_wl >= chunk 20th; Tq = min_w T_wl
//      >= query's global 20th distance (provable bound).
//  P2: 64-bucket linear histogram of dist<=Tq over [0,Tq] (monotone map).
//  P3: collect bucket <= b* as packed (dist,idx) u64 into LDS list.
//  P4: selection-sort first 20 -> exact (dist,idx) order == lax.top_k.
// ======================================================================
__global__ __launch_bounds__(512) void knn_select_kernel(const float4* __restrict__ xyz4,
                                                         unsigned short* __restrict__ nidx) {
  __shared__ unsigned int hist[64 * 65];           // [lane][bucket], stride 65 (bank pad)
  __shared__ float twl[8 * 64];                    // [wave][lane]
  __shared__ unsigned int qcnt[64];
  __shared__ unsigned int qbsA[64];
  __shared__ unsigned int qover[64];
  __shared__ unsigned long long lst[64 * 65];      // [lane][slot], stride 65 (bank pad)

  const int t = threadIdx.x;
  const int w = t >> 6, l = t & 63;
  const int batch = blockIdx.x >> 7;               // 128 blocks per batch
  const int q0 = (blockIdx.x & 127) << 6;          // 64 queries per block
  const float4* __restrict__ xb = xyz4 + batch * N_PTS;
  const float4 qv = xb[q0 + l];

  for (int i = t; i < 64 * 65; i += 512) hist[i] = 0;
  if (t < 64) { qcnt[t] = 0; qover[t] = 0; }

  const int base = __builtin_amdgcn_readfirstlane(w * 1024);

  // ---- Phase 1: stripe minima -> wave-chunk bound ----
  float m20[20];
#pragma unroll
  for (int u = 0; u < 20; ++u) m20[u] = INFINITY;
  for (int i = 0; i < 1020; i += 20) {
#pragma unroll
    for (int u = 0; u < 20; ++u) {
      float4 cv = xb[base + i + u];
      m20[u] = fminf(m20[u], qdist(qv, cv));
    }
  }
#pragma unroll
  for (int u = 0; u < 4; ++u) {
    float4 cv = xb[base + 1020 + u];
    m20[u] = fminf(m20[u], qdist(qv, cv));
  }
  float T = m20[0];
#pragma unroll
  for (int u = 1; u < 20; ++u) T = fmaxf(T, m20[u]);
  twl[w * 64 + l] = T;
  __syncthreads();

  float Tq = twl[l];
#pragma unroll
  for (int ww = 1; ww < 8; ++ww) Tq = fminf(Tq, twl[ww * 64 + l]);
  const float scale = (Tq > 0.0f) ? (64.0f / Tq) : 0.0f;

  // ---- Phase 2: histogram ----
  for (int i = 0; i < 1024; ++i) {
    float4 cv = xb[base + i];
    float dist = qdist(qv, cv);
    if (dist <= Tq) {
      int bkt = (int)(dist * scale);
      bkt = min(63, max(0, bkt));
      atomicAdd(&hist[l * 65 + bkt], 1u);
    }
  }
  __syncthreads();

  // ---- b* per query ----
  if (t < 64) {
    unsigned int cum = 0; int bs = 63;
    for (int j = 0; j < 64; ++j) {
      unsigned int c = hist[t * 65 + j];
      if (cum + c >= 20u) { bs = j; break; }
      cum += c;
    }
    qbsA[t] = (unsigned int)bs;
  }
  __syncthreads();
  const int bs = (int)qbsA[l];

  // ---- Phase 3: collect ----
  for (int i = 0; i < 1024; ++i) {
    float4 cv = xb[base + i];
    float dist = qdist(qv, cv);
    if (dist <= Tq) {
      int bkt = (int)(dist * scale);
      bkt = min(63, max(0, bkt));
      if (bkt <= bs) {
        unsigned int pos = atomicAdd(&qcnt[l], 1u);
        if (pos < CAP) lst[l * 65 + pos] = packdi(dist, base + i);
        else qover[l] = 1u;
      }
    }
  }
  __syncthreads();

  // ---- Phase 4: exact top-20 (sorted by (dist, idx)) ----
  if (t < 64) {
    unsigned int n = qcnt[t];
    unsigned short* oq = nidx + ((size_t)(batch * N_PTS + q0 + t)) * KNN;
    if (qover[t] || n > CAP) {
      // exact serial fallback (~never taken; correctness guarantee)
      unsigned long long best[KNN];
#pragma unroll
      for (int j = 0; j < KNN; ++j) best[j] = ~0ULL;
      for (int m = 0; m < N_PTS; ++m) {
        float dist = qdist(qv, xb[m]);
        unsigned long long p = packdi(dist, m);
        if (p < best[KNN - 1]) {
          int j = KNN - 1;
          while (j > 0 && best[j - 1] > p) { best[j] = best[j - 1]; --j; }
          best[j] = p;
        }
      }
      for (int j = 0; j < KNN; ++j) oq[j] = (unsigned short)(best[j] & 0xffffu);
    } else {
      for (int j = 0; j < KNN; ++j) {
        unsigned long long bestv = ~0ULL; unsigned int bk = 0;
        for (unsigned int k = 0; k < n; ++k) {
          unsigned long long v = lst[t * 65 + k];
          if (v < bestv) { bestv = v; bk = k; }
        }
        lst[t * 65 + bk] = ~0ULL;
        oq[j] = (unsigned short)(bestv & 0xffffu);
      }
    }
  }
}

// ======================================================================
// Kernel 2: covariance (in sorted-neighbor order) + eigh -> normals.
// One thread per query; fully parallel eigh.
// ======================================================================
__global__ __launch_bounds__(256) void normals_kernel(const float4* __restrict__ xyz4,
                                                      const unsigned short* __restrict__ nidx,
                                                      float4* __restrict__ nrm4) {
  int gid = blockIdx.x * 256 + threadIdx.x;        // 0..32767
  int batch = gid >> 13, q = gid & (N_PTS - 1);
  const float4* __restrict__ xb = xyz4 + batch * N_PTS;
  const float4 qv = xb[q];
  const unsigned short* iq = nidx + (size_t)gid * KNN;
  float c00, c01, c02, c11, c12, c22;
  {
#pragma clang fp contract(off)
    c00 = 0.f; c01 = 0.f; c02 = 0.f; c11 = 0.f; c12 = 0.f; c22 = 0.f;
    for (int j = 0; j < KNN; ++j) {
      float4 pv = xb[iq[j]];
      float dx = pv.x - qv.x, dy = pv.y - qv.y, dz = pv.z - qv.z;
      c00 = c00 + dx * dx; c01 = c01 + dx * dy; c02 = c02 + dx * dz;
      c11 = c11 + dy * dy; c12 = c12 + dy * dz; c22 = c22 + dz * dz;
    }
  }
  float ev[3];
  eigh3_smallest(c00, c01, c02, c11, c12, c22, ev);
  nrm4[gid] = make_float4(ev[0], ev[1], ev[2], 0.0f);
}

// ======================================================================
// Kernel 3: GEMM1 (w1 @ [x; normals] + b1) -> per-channel sum/sumsq
// ======================================================================
__global__ __launch_bounds__(256) void gemm1_stats_kernel(const float* __restrict__ x,
                                                          const float4* __restrict__ nrm4,
                                                          const float* __restrict__ w1t,
                                                          const float* __restrict__ b1,
                                                          float* __restrict__ sums,
                                                          float* __restrict__ sumsq) {
  __shared__ float lds[64 * 134];
  const int t = threadIdx.x;
  const int b = blockIdx.x >> 7;
  const int n0 = (blockIdx.x & 127) << 6;
  for (int idx = t; idx < CH * 64; idx += 256) {
    int cc = idx >> 6, nl = idx & 63;
    lds[nl * 134 + cc] = x[((size_t)(b * CH + cc)) * N_PTS + n0 + nl];
  }
  if (t < 64) {
    float4 nv = nrm4[b * N_PTS + n0 + t];
    lds[t * 134 + 128] = nv.x; lds[t * 134 + 129] = nv.y;
    lds[t * 134 + 130] = nv.z; lds[t * 134 + 131] = 0.0f;
  }
  __syncthreads();

  const int og = __builtin_amdgcn_readfirstlane(t >> 6);
  const int nl = t & 63;
  float acc[32];
#pragma unroll
  for (int k = 0; k < 32; ++k) acc[k] = b1[og * 32 + k];
  for (int c2 = 0; c2 < 66; ++c2) {
    float2 xv = *(const float2*)&lds[nl * 134 + 2 * c2];
    const float* wr0 = w1t + (2 * c2) * CH + og * 32;
    const float* wr1 = wr0 + CH;
#pragma unroll
    for (int k = 0; k < 32; ++k) acc[k] = fmaf(wr0[k], xv.x, acc[k]);
#pragma unroll
    for (int k = 0; k < 32; ++k) acc[k] = fmaf(wr1[k], xv.y, acc[k]);
  }
  __syncthreads();
#pragma unroll
  for (int k2 = 0; k2 < 16; ++k2)
    *(float2*)&lds[nl * 134 + og * 32 + 2 * k2] = make_float2(acc[2 * k2], acc[2 * k2 + 1]);
  __syncthreads();
  {
    int cc = t & 127, hf = t >> 7;
    float sm = 0.f, sq = 0.f;
    for (int rr = hf * 32; rr < hf * 32 + 32; ++rr) {
      float v = lds[rr * 134 + cc];
      sm += v; sq = fmaf(v, v, sq);
    }
    atomicAdd(&sums[cc], sm);
    atomicAdd(&sumsq[cc], sq);
  }
}

// ======================================================================
// Kernel 4: finalize BN scale/shift (double precision)
// ======================================================================
__global__ void bn_finalize_kernel(const float* __restrict__ sums, const float* __restrict__ sumsq,
                                   const float* __restrict__ gamma, const float* __restrict__ beta,
                                   float* __restrict__ scale, float* __restrict__ shift) {
  int c = threadIdx.x;
  if (c < CH) {
    const double cnt = (double)(BATCH * N_PTS);
    double mean = (double)sums[c] / cnt;
    double var = (double)sumsq[c] / cnt - mean * mean;
    double inv = 1.0 / sqrt(var + 1e-5);
    double sc = (double)gamma[c] * inv;
    scale[c] = (float)sc;
    shift[c] = (float)((double)beta[c] - mean * sc);
  }
}

// ======================================================================
// Kernel 5: fused GEMM1 (recompute) + BN + ReLU + GEMM2 -> out
// ======================================================================
__global__ __launch_bounds__(256) void fused_out_kernel(const float* __restrict__ x,
                                                        const float4* __restrict__ nrm4,
                                                        const float* __restrict__ w1t,
                                                        const float* __restrict__ b1,
                                                        const float* __restrict__ w2t,
                                                        const float* __restrict__ b2,
                                                        const float* __restrict__ scale,
                                                        const float* __restrict__ shift,
                                                        float* __restrict__ out) {
  __shared__ float lds[64 * 134];
  const int t = threadIdx.x;
  const int b = blockIdx.x >> 7;
  const int n0 = (blockIdx.x & 127) << 6;
  for (int idx = t; idx < CH * 64; idx += 256) {
    int cc = idx >> 6, nl = idx & 63;
    lds[nl * 134 + cc] = x[((size_t)(b * CH + cc)) * N_PTS + n0 + nl];
  }
  if (t < 64) {
    float4 nv = nrm4[b * N_PTS + n0 + t];
    lds[t * 134 + 128] = nv.x; lds[t * 134 + 129] = nv.y;
    lds[t * 134 + 130] = nv.z; lds[t * 134 + 131] = 0.0f;
  }
  __syncthreads();

  const int og = __builtin_amdgcn_readfirstlane(t >> 6);
  const int nl = t & 63;
  float acc[32];
#pragma unroll
  for (int k = 0; k < 32; ++k) acc[k] = b1[og * 32 + k];
  for (int c2 = 0; c2 < 66; ++c2) {
    float2 xv = *(const float2*)&lds[nl * 134 + 2 * c2];
    const float* wr0 = w1t + (2 * c2) * CH + og * 32;
    const float* wr1 = wr0 + CH;
#pragma unroll
    for (int k = 0; k < 32; ++k) acc[k] = fmaf(wr0[k], xv.x, acc[k]);
#pragma unroll
    for (int k = 0; k < 32; ++k) acc[k] = fmaf(wr1[k], xv.y, acc[k]);
  }
#pragma unroll
  for (int k = 0; k < 32; ++k) {
    float sc = scale[og * 32 + k], sh = shift[og * 32 + k];
    acc[k] = fmaxf(fmaf(acc[k], sc, sh), 0.0f);
  }
  __syncthreads();
#pragma unroll
  for (int k2 = 0; k2 < 16; ++k2)
    *(float2*)&lds[nl * 134 + og * 32 + 2 * k2] = make_float2(acc[2 * k2], acc[2 * k2 + 1]);
  __syncthreads();

  float acc2[32];
#pragma unroll
  for (int k = 0; k < 32; ++k) acc2[k] = b2[og * 32 + k];
  for (int c2 = 0; c2 < 64; ++c2) {
    float2 hv = *(const float2*)&lds[nl * 134 + 2 * c2];
    const float* wr0 = w2t + (2 * c2) * CH + og * 32;
    const float* wr1 = wr0 + CH;
#pragma unroll
    for (int k = 0; k < 32; ++k) acc2[k] = fmaf(wr0[k], hv.x, acc2[k]);
#pragma unroll
    for (int k = 0; k < 32; ++k) acc2[k] = fmaf(wr1[k], hv.y, acc2[k]);
  }
#pragma unroll
  for (int k = 0; k < 32; ++k) {
    int o = og * 32 + k;
    out[((size_t)(b * CH + o)) * N_PTS + n0 + nl] = acc2[k];
  }
}

// ======================================================================
extern "C" void kernel_launch(void* const* d_in, const int* in_sizes, int n_in,
                              void* d_out, int out_size, void* d_ws, size_t ws_size,
                              hipStream_t stream) {
  const float* x     = (const float*)d_in[0];
  const float* xyz   = (const float*)d_in[1];
  const float* w1    = (const float*)d_in[2];
  const float* b1    = (const float*)d_in[3];
  const float* gamma = (const float*)d_in[4];
  const float* beta  = (const float*)d_in[5];
  const float* w2    = (const float*)d_in[6];
  const float* b2    = (const float*)d_in[7];
  float* out = (float*)d_out;

  float* W = (float*)d_ws;
  float4* xyz4 = (float4*)W;                         // 131072 floats
  float4* nrm4 = (float4*)(W + 131072);              // 131072 floats
  float* w1t   = W + 262144;                         // 132*128 = 16896
  float* w2t   = W + 279040;                         // 128*128 = 16384
  float* stats = W + 295424;                         // sums[128] | sumsq[128]
  float* scale = W + 295680;                         // 128
  float* shift = W + 295808;                         // 128
  unsigned short* nidx = (unsigned short*)(W + 295936);  // 32768*20 u16 = 1.31 MB

  prep_kernel<<<128, 256, 0, stream>>>(xyz, w1, w2, xyz4, w1t, w2t, stats);
  knn_select_kernel<<<BATCH * N_PTS / 64, 512, 0, stream>>>(xyz4, nidx);
  normals_kernel<<<BATCH * N_PTS / 256, 256, 0, stream>>>(xyz4, nidx, nrm4);
  gemm1_stats_kernel<<<BATCH * N_PTS / 64, 256, 0, stream>>>(x, nrm4, w1t, b1, stats, stats + 128);
  bn_finalize_kernel<<<1, 128, 0, stream>>>(stats, stats + 128, gamma, beta, scale, shift);
  fused_out_kernel<<<BATCH * N_PTS / 64, 256, 0, stream>>>(x, nrm4, w1t, b1, w2t, b2, scale, shift, out);
}

// Round 4
// 377.684 us; speedup vs baseline: 2.9605x; 1.2390x over previous
//
#include <hip/hip_runtime.h>
#include <math.h>

#define N_PTS 8192
#define BATCH 4
#define CH 128
#define KNN 20
#define CAP 112
#define POOL 256

// ======================================================================
// LAPACK ssyevd emulation for 3x3 symmetric (lower), SINGLE precision,
// matching numpy's float32 eigh path bit-for-bit where decisions matter.
// (verified passing in rounds 2-3 — do not perturb numerics)
// ======================================================================

__device__ __forceinline__ float slapy2f(float x, float y) {
#pragma clang fp contract(off)
  float ax = fabsf(x), ay = fabsf(y);
  float w = fmaxf(ax, ay), z = fminf(ax, ay);
  if (z == 0.0f) return w;
  float t = z / w;
  return w * sqrtf(1.0f + t * t);
}

__device__ __forceinline__ void slartgf(float f, float g, float* cs, float* sn, float* r) {
#pragma clang fp contract(off)
  if (g == 0.0f) { *cs = 1.0f; *sn = 0.0f; *r = f; }
  else if (f == 0.0f) { *cs = 0.0f; *sn = copysignf(1.0f, g); *r = fabsf(g); }
  else {
    float f1 = fabsf(f);
    float d = sqrtf(f * f + g * g);
    *cs = f1 / d;
    *r = copysignf(d, f);
    *sn = g / (*r);
  }
}

__device__ void slaev2f(float a, float b, float c, float* rt1, float* rt2,
                        float* cs1, float* sn1) {
#pragma clang fp contract(off)
  float sm = a + c, df = a - c, adf = fabsf(df);
  float tb = b + b, ab = fabsf(tb);
  float acmx, acmn;
  if (fabsf(a) > fabsf(c)) { acmx = a; acmn = c; } else { acmx = c; acmn = a; }
  float rt;
  if (adf > ab)      { float q = ab / adf;  rt = adf * sqrtf(1.0f + q * q); }
  else if (adf < ab) { float q = adf / ab;  rt = ab * sqrtf(1.0f + q * q); }
  else               rt = ab * sqrtf(2.0f);
  int sgn1;
  if (sm < 0.0f)      { *rt1 = 0.5f * (sm - rt); sgn1 = -1; *rt2 = (acmx / *rt1) * acmn - (b / *rt1) * b; }
  else if (sm > 0.0f) { *rt1 = 0.5f * (sm + rt); sgn1 = 1;  *rt2 = (acmx / *rt1) * acmn - (b / *rt1) * b; }
  else                { *rt1 = 0.5f * rt; *rt2 = -0.5f * rt; sgn1 = 1; }
  float cs; int sgn2;
  if (df >= 0.0f) { cs = df + rt; sgn2 = 1; } else { cs = df - rt; sgn2 = -1; }
  float acs = fabsf(cs);
  if (acs > ab) {
    float ct = -tb / cs;
    *sn1 = 1.0f / sqrtf(1.0f + ct * ct);
    *cs1 = ct * (*sn1);
  } else {
    if (ab == 0.0f) { *cs1 = 1.0f; *sn1 = 0.0f; }
    else {
      float tn = -cs / tb;
      *cs1 = 1.0f / sqrtf(1.0f + tn * tn);
      *sn1 = tn * (*cs1);
    }
  }
  if (sgn1 == sgn2) { float tn = *cs1; *cs1 = -(*sn1); *sn1 = tn; }
}

__device__ void eigh3_smallest(float a00, float a10, float a20,
                               float a11, float a21, float a22, float evec[3]) {
#pragma clang fp contract(off)
  float d[3], e[2], tau = 0.0f, v2 = 0.0f;
  d[0] = a00;
  {
    float xnorm = sqrtf(a20 * a20);   // snrm2(1)
    if (xnorm == 0.0f) {
      tau = 0.0f; v2 = 0.0f;
      e[0] = a10; d[1] = a11; e[1] = a21; d[2] = a22;
    } else {
      float alpha = a10;
      float beta = -copysignf(slapy2f(alpha, xnorm), alpha);
      tau = (beta - alpha) / beta;
      float invs = 1.0f / (alpha - beta);
      v2 = a20 * invs;
      e[0] = beta;
      float y0 = tau * a11;
      float y1 = tau * a21;
      y0 = y0 + tau * (a21 * v2);
      y1 = y1 + (tau * v2) * a22;
      float dot = y0 + y1 * v2;
      float al = (-0.5f * tau) * dot;
      float w0 = y0 + al;
      float w1 = y1 + al * v2;
      a11 = (a11 - w0) - w0;
      a21 = (a21 - v2 * w0) - w1;
      a22 = (a22 - v2 * w1) - w1 * v2;
      d[1] = a11; e[1] = a21; d[2] = a22;
    }
  }

  float z[3][3] = {{1.0f,0.0f,0.0f},{0.0f,1.0f,0.0f},{0.0f,0.0f,1.0f}};
  const float eps = 5.9604644775390625e-08f;
  const float eps2 = 3.5527136788005009e-15f;
  const float safmin = 1.1754943508222875e-38f;
  int nmaxit = 90, jtot = 0;
  int l1 = 0;
  int l, m, lend, lsv, lendsv;
  float p, g, r, c, s, f, b_, rt1, rt2, tst;
  float wc[2], wsn[2];

outer_loop:
  if (l1 > 2) goto sorting;
  if (l1 > 0) e[l1 - 1] = 0.0f;
  {
    int mm;
    for (mm = l1; mm <= 1; ++mm) {
      tst = fabsf(e[mm]);
      if (tst == 0.0f) break;
      if (tst <= (sqrtf(fabsf(d[mm])) * sqrtf(fabsf(d[mm + 1]))) * eps) { e[mm] = 0.0f; break; }
    }
    m = (mm > 1) ? 2 : mm;
  }
  l = l1; lsv = l; lend = m; lendsv = lend; l1 = m + 1;
  if (lend == l) goto outer_loop;
  {
    float an = 0.0f;
    for (int i2 = l; i2 <= lend; ++i2) an = fmaxf(an, fabsf(d[i2]));
    for (int i2 = l; i2 < lend; ++i2) an = fmaxf(an, fabsf(e[i2]));
    if (an == 0.0f) goto outer_loop;
  }
  if (fabsf(d[lend]) < fabsf(d[l])) { lend = lsv; l = lendsv; }

  if (lend > l) {
ql40:
    if (l != lend) {
      for (m = l; m <= lend - 1; ++m) {
        tst = e[m] * e[m];
        if (tst <= (eps2 * fabsf(d[m])) * fabsf(d[m + 1]) + safmin) goto ql60;
      }
    }
    m = lend;
ql60:
    if (m < lend) e[m] = 0.0f;
    p = d[l];
    if (m == l) goto ql80;
    if (m == l + 1) {
      slaev2f(d[l], e[l], d[l + 1], &rt1, &rt2, &c, &s);
      for (int i2 = 0; i2 < 3; ++i2) {
        float temp = z[i2][l + 1];
        z[i2][l + 1] = c * temp - s * z[i2][l];
        z[i2][l]     = s * temp + c * z[i2][l];
      }
      d[l] = rt1; d[l + 1] = rt2; e[l] = 0.0f;
      l += 2;
      if (l <= lend) goto ql40;
      goto done140;
    }
    if (jtot == nmaxit) goto done140;
    jtot++;
    g = (d[l + 1] - p) / (2.0f * e[l]);
    r = slapy2f(g, 1.0f);
    g = d[m] - p + e[l] / (g + copysignf(r, g));
    s = 1.0f; c = 1.0f; p = 0.0f;
    for (int i2 = m - 1; i2 >= l; --i2) {
      f = s * e[i2]; b_ = c * e[i2];
      slartgf(g, f, &c, &s, &r);
      if (i2 != m - 1) e[i2 + 1] = r;
      g = d[i2 + 1] - p;
      r = (d[i2] - g) * s + 2.0f * c * b_;
      p = s * r;
      d[i2 + 1] = g + p;
      g = c * r - b_;
      wc[i2] = c; wsn[i2] = -s;
    }
    for (int j = m - 1; j >= l; --j) {
      float ct = wc[j], st = wsn[j];
      for (int i2 = 0; i2 < 3; ++i2) {
        float temp = z[i2][j + 1];
        z[i2][j + 1] = ct * temp - st * z[i2][j];
        z[i2][j]     = st * temp + ct * z[i2][j];
      }
    }
    d[l] -= p;
    e[l] = g;
    goto ql40;
ql80:
    d[l] = p;
    l += 1;
    if (l <= lend) goto ql40;
    goto done140;
  } else {
qr90:
    if (l != lend) {
      for (m = l; m >= lend + 1; --m) {
        tst = e[m - 1] * e[m - 1];
        if (tst <= (eps2 * fabsf(d[m])) * fabsf(d[m - 1]) + safmin) goto qr110;
      }
    }
    m = lend;
qr110:
    if (m > lend) e[m - 1] = 0.0f;
    p = d[l];
    if (m == l) goto qr130;
    if (m == l - 1) {
      slaev2f(d[l - 1], e[l - 1], d[l], &rt1, &rt2, &c, &s);
      for (int i2 = 0; i2 < 3; ++i2) {
        float temp = z[i2][l];
        z[i2][l]     = c * temp - s * z[i2][l - 1];
        z[i2][l - 1] = s * temp + c * z[i2][l - 1];
      }
      d[l - 1] = rt1; d[l] = rt2; e[l - 1] = 0.0f;
      l -= 2;
      if (l >= lend) goto qr90;
      goto done140;
    }
    if (jtot == nmaxit) goto done140;
    jtot++;
    g = (d[l - 1] - p) / (2.0f * e[l - 1]);
    r = slapy2f(g, 1.0f);
    g = d[m] - p + e[l - 1] / (g + copysignf(r, g));
    s = 1.0f; c = 1.0f; p = 0.0f;
    for (int i2 = m; i2 <= l - 1; ++i2) {
      f = s * e[i2]; b_ = c * e[i2];
      slartgf(g, f, &c, &s, &r);
      if (i2 != m) e[i2 - 1] = r;
      g = d[i2] - p;
      r = (d[i2 + 1] - g) * s + 2.0f * c * b_;
      p = s * r;
      d[i2] = g + p;
      g = c * r - b_;
      wc[i2] = c; wsn[i2] = s;
    }
    for (int j = m; j <= l - 1; ++j) {
      float ct = wc[j], st = wsn[j];
      for (int i2 = 0; i2 < 3; ++i2) {
        float temp = z[i2][j + 1];
        z[i2][j + 1] = ct * temp - st * z[i2][j];
        z[i2][j]     = st * temp + ct * z[i2][j];
      }
    }
    d[l] -= p;
    e[l - 1] = g;
    goto qr90;
qr130:
    d[l] = p;
    l -= 1;
    if (l >= lend) goto qr90;
    goto done140;
  }
done140:
  if (jtot < nmaxit) goto outer_loop;
sorting:
  for (int ii = 1; ii <= 2; ++ii) {
    int i_ = ii - 1, k = i_;
    p = d[i_];
    for (int j = ii; j <= 2; ++j) if (d[j] < p) { k = j; p = d[j]; }
    if (k != i_) {
      d[k] = d[i_]; d[i_] = p;
      for (int i2 = 0; i2 < 3; ++i2) { float tz = z[i2][i_]; z[i2][i_] = z[i2][k]; z[i2][k] = tz; }
    }
  }
  {
    float z10 = z[1][0], z20 = z[2][0];
    float sum = z10 + v2 * z20;
    evec[0] = z[0][0];
    evec[1] = z10 - tau * sum;
    evec[2] = z20 - tau * sum * v2;
  }
}

// ======================================================================
// Kernel 0: prep
// ======================================================================
__global__ __launch_bounds__(256) void prep_kernel(const float* __restrict__ xyz,
                                                   const float* __restrict__ w1,
                                                   const float* __restrict__ w2,
                                                   float4* __restrict__ xyz4,
                                                   float* __restrict__ w1t,
                                                   float* __restrict__ w2t,
                                                   float* __restrict__ stats) {
  int idx = blockIdx.x * 256 + threadIdx.x;
  if (idx < BATCH * N_PTS) {
    float x = xyz[idx * 3], y = xyz[idx * 3 + 1], zz = xyz[idx * 3 + 2];
    float sq = fmaf(zz, zz, fmaf(y, y, x * x));
    xyz4[idx] = make_float4(x, y, zz, sq);
  }
  if (idx < 132 * CH) {
    int cc = idx >> 7, o = idx & 127;
    w1t[idx] = (cc < 131) ? w1[o * 131 + cc] : 0.0f;
  }
  if (idx < CH * CH) {
    int cc = idx >> 7, o = idx & 127;
    w2t[idx] = w2[o * CH + cc];
  }
  if (idx < 256) stats[idx] = 0.0f;
}

__device__ __forceinline__ float qdist(const float4 qv, const float4 cv) {
  float dot = fmaf(qv.x, cv.x, fmaf(qv.y, cv.y, qv.z * cv.z));
  return fmaf(-2.0f, dot, qv.w + cv.w);
}

__device__ __forceinline__ unsigned int distbits(float dist) {
  unsigned int du = __float_as_uint(dist);
  return (du & 0x80000000u) ? ~du : (du | 0x80000000u);  // monotone total order
}

// ======================================================================
// Kernel 1: exact 20-NN, two scans.
//  P1: per (lane=query, wave=chunk of 1024) exact 3 smallest via branchless
//      min/max network; Tq = MAX over 8 chunks of chunk-3rd  =>
//      >= 24 candidates <= Tq  =>  Tq >= global 20th NN distance (exact bound).
//  P2: collect dist<=Tq as (distbits|qid|idx) u64 into per-query LDS list
//      (CAP=112); rare spill to shared 256-entry pool (qid-tagged).
//  P3: 8-lane-parallel selection of top-20 by (dist,idx) == lax.top_k order.
// ======================================================================
__global__ __launch_bounds__(512) void knn_select_kernel(const float4* __restrict__ xyz4,
                                                         unsigned short* __restrict__ nidx) {
  __shared__ unsigned long long lst[64 * (CAP + 2)];   // stride 114 (228 words ≡ 4 mod 32)
  __shared__ unsigned long long pool[POOL];
  __shared__ float bnd[8 * 64];
  __shared__ unsigned int qcnt[64];
  __shared__ unsigned int qflag[64];
  __shared__ unsigned int qover[64];
  __shared__ unsigned int pool_cnt;

  const int t = threadIdx.x;
  const int w = t >> 6, l = t & 63;
  const int batch = blockIdx.x >> 7;               // 128 blocks per batch
  const int q0 = (blockIdx.x & 127) << 6;          // 64 queries per block
  const float4* __restrict__ xb = xyz4 + batch * N_PTS;
  const float4 qv = xb[q0 + l];

  if (t < 64) { qcnt[t] = 0; qflag[t] = 0; qover[t] = 0; }
  if (t == 0) pool_cnt = 0;
  __syncthreads();

  const int base = __builtin_amdgcn_readfirstlane(w * 1024);

  // ---- Phase 1: exact 3-smallest per chunk (branchless network) ----
  float c0 = INFINITY, c1 = INFINITY, c2 = INFINITY;
#pragma unroll 8
  for (int i = 0; i < 1024; ++i) {
    float4 cv = xb[base + i];
    float dist = qdist(qv, cv);
    float t0 = fmaxf(c0, dist); c0 = fminf(c0, dist);
    float t1 = fmaxf(c1, t0);   c1 = fminf(c1, t0);
    c2 = fminf(c2, t1);
  }
  bnd[w * 64 + l] = c2;
  __syncthreads();

  float Tq = bnd[l];
#pragma unroll
  for (int ww = 1; ww < 8; ++ww) Tq = fmaxf(Tq, bnd[ww * 64 + l]);

  // ---- Phase 2: collect ----
#pragma unroll 4
  for (int i = 0; i < 1024; ++i) {
    float4 cv = xb[base + i];
    float dist = qdist(qv, cv);
    if (dist <= Tq) {
      unsigned long long key = ((unsigned long long)distbits(dist) << 32)
                             | ((unsigned int)l << 16) | (unsigned int)(base + i);
      unsigned int pos = atomicAdd(&qcnt[l], 1u);
      if (pos < CAP) lst[l * (CAP + 2) + pos] = key;
      else {
        unsigned int pp = atomicAdd(&pool_cnt, 1u);
        if (pp < POOL) { pool[pp] = key; qflag[l] = 1u; }
        else qover[l] = 1u;
      }
    }
  }
  __syncthreads();

  // ---- Phase 3: parallel top-20 (8 lanes per query) ----
  const int qg = t >> 3, sub = t & 7;
  unsigned int n = qcnt[qg]; if (n > CAP) n = CAP;
  const unsigned int pcnt = (qflag[qg] && !qover[qg]) ? min(pool_cnt, (unsigned int)POOL) : 0u;
  unsigned short* oq = nidx + ((size_t)(batch * N_PTS + q0 + qg)) * KNN;

  if (qover[qg]) {
    if (sub == 0) {
      // exact serial fallback (astronomically rare)
      unsigned long long best[KNN];
#pragma unroll
      for (int j = 0; j < KNN; ++j) best[j] = ~0ULL;
      const float4 qv2 = xb[qg + q0 - q0 + qg >= 0 ? (q0 + qg) : 0];  // xb[q0+qg]
      for (int m = 0; m < N_PTS; ++m) {
        float dist = qdist(qv2, xb[m]);
        unsigned long long p = ((unsigned long long)distbits(dist) << 32) | (unsigned int)m;
        if (p < best[KNN - 1]) {
          int j = KNN - 1;
          while (j > 0 && best[j - 1] > p) { best[j] = best[j - 1]; --j; }
          best[j] = p;
        }
      }
      for (int j = 0; j < KNN; ++j) oq[j] = (unsigned short)(best[j] & 0xffffu);
    }
  } else {
    for (int r = 0; r < KNN; ++r) {
      unsigned long long best = ~0ULL; int bslot = 0;
      for (unsigned int s = sub; s < n; s += 8) {
        unsigned long long v = lst[qg * (CAP + 2) + s];
        if (v < best) { best = v; bslot = (int)s; }
      }
      for (unsigned int s = sub; s < pcnt; s += 8) {
        unsigned long long v = pool[s];
        if ((unsigned int)((v >> 16) & 0xffffu) == (unsigned int)qg && v < best) {
          best = v; bslot = 0x10000 | (int)s;
        }
      }
#pragma unroll
      for (int mm = 1; mm < 8; mm <<= 1) {
        unsigned long long ob = __shfl_xor(best, mm, 64);
        int obs = __shfl_xor(bslot, mm, 64);
        if (ob < best) { best = ob; bslot = obs; }
      }
      int s = bslot & 0xffff;
      if ((s & 7) == sub) {
        if (bslot & 0x10000) pool[s] = ~0ULL;
        else lst[qg * (CAP + 2) + s] = ~0ULL;
      }
      if (sub == 0) oq[r] = (unsigned short)(best & 0xffffu);
    }
  }
}

// ======================================================================
// Kernel 2: covariance (sorted order) + eigh -> normals
// ======================================================================
__global__ __launch_bounds__(256) void normals_kernel(const float4* __restrict__ xyz4,
                                                      const unsigned short* __restrict__ nidx,
                                                      float4* __restrict__ nrm4) {
  int gid = blockIdx.x * 256 + threadIdx.x;
  int batch = gid >> 13, q = gid & (N_PTS - 1);
  const float4* __restrict__ xb = xyz4 + batch * N_PTS;
  const float4 qv = xb[q];
  const unsigned short* iq = nidx + (size_t)gid * KNN;
  float c00, c01, c02, c11, c12, c22;
  {
#pragma clang fp contract(off)
    c00 = 0.f; c01 = 0.f; c02 = 0.f; c11 = 0.f; c12 = 0.f; c22 = 0.f;
    for (int j = 0; j < KNN; ++j) {
      float4 pv = xb[iq[j]];
      float dx = pv.x - qv.x, dy = pv.y - qv.y, dz = pv.z - qv.z;
      c00 = c00 + dx * dx; c01 = c01 + dx * dy; c02 = c02 + dx * dz;
      c11 = c11 + dy * dy; c12 = c12 + dy * dz; c22 = c22 + dz * dz;
    }
  }
  float ev[3];
  eigh3_smallest(c00, c01, c02, c11, c12, c22, ev);
  nrm4[gid] = make_float4(ev[0], ev[1], ev[2], 0.0f);
}

// ======================================================================
// Kernel 3: GEMM1 + BN stats
// ======================================================================
__global__ __launch_bounds__(256) void gemm1_stats_kernel(const float* __restrict__ x,
                                                          const float4* __restrict__ nrm4,
                                                          const float* __restrict__ w1t,
                                                          const float* __restrict__ b1,
                                                          float* __restrict__ sums,
                                                          float* __restrict__ sumsq) {
  __shared__ float lds[64 * 134];
  const int t = threadIdx.x;
  const int b = blockIdx.x >> 7;
  const int n0 = (blockIdx.x & 127) << 6;
  for (int idx = t; idx < CH * 64; idx += 256) {
    int cc = idx >> 6, nl = idx & 63;
    lds[nl * 134 + cc] = x[((size_t)(b * CH + cc)) * N_PTS + n0 + nl];
  }
  if (t < 64) {
    float4 nv = nrm4[b * N_PTS + n0 + t];
    lds[t * 134 + 128] = nv.x; lds[t * 134 + 129] = nv.y;
    lds[t * 134 + 130] = nv.z; lds[t * 134 + 131] = 0.0f;
  }
  __syncthreads();

  const int og = __builtin_amdgcn_readfirstlane(t >> 6);
  const int nl = t & 63;
  float acc[32];
#pragma unroll
  for (int k = 0; k < 32; ++k) acc[k] = b1[og * 32 + k];
  for (int c2 = 0; c2 < 66; ++c2) {
    float2 xv = *(const float2*)&lds[nl * 134 + 2 * c2];
    const float* wr0 = w1t + (2 * c2) * CH + og * 32;
    const float* wr1 = wr0 + CH;
#pragma unroll
    for (int k = 0; k < 32; ++k) acc[k] = fmaf(wr0[k], xv.x, acc[k]);
#pragma unroll
    for (int k = 0; k < 32; ++k) acc[k] = fmaf(wr1[k], xv.y, acc[k]);
  }
  __syncthreads();
#pragma unroll
  for (int k2 = 0; k2 < 16; ++k2)
    *(float2*)&lds[nl * 134 + og * 32 + 2 * k2] = make_float2(acc[2 * k2], acc[2 * k2 + 1]);
  __syncthreads();
  {
    int cc = t & 127, hf = t >> 7;
    float sm = 0.f, sq = 0.f;
    for (int rr = hf * 32; rr < hf * 32 + 32; ++rr) {
      float v = lds[rr * 134 + cc];
      sm += v; sq = fmaf(v, v, sq);
    }
    atomicAdd(&sums[cc], sm);
    atomicAdd(&sumsq[cc], sq);
  }
}

// ======================================================================
// Kernel 4: finalize BN scale/shift
// ======================================================================
__global__ void bn_finalize_kernel(const float* __restrict__ sums, const float* __restrict__ sumsq,
                                   const float* __restrict__ gamma, const float* __restrict__ beta,
                                   float* __restrict__ scale, float* __restrict__ shift) {
  int c = threadIdx.x;
  if (c < CH) {
    const double cnt = (double)(BATCH * N_PTS);
    double mean = (double)sums[c] / cnt;
    double var = (double)sumsq[c] / cnt - mean * mean;
    double inv = 1.0 / sqrt(var + 1e-5);
    double sc = (double)gamma[c] * inv;
    scale[c] = (float)sc;
    shift[c] = (float)((double)beta[c] - mean * sc);
  }
}

// ======================================================================
// Kernel 5: fused GEMM1 (recompute) + BN + ReLU + GEMM2 -> out
// ======================================================================
__global__ __launch_bounds__(256) void fused_out_kernel(const float* __restrict__ x,
                                                        const float4* __restrict__ nrm4,
                                                        const float* __restrict__ w1t,
                                                        const float* __restrict__ b1,
                                                        const float* __restrict__ w2t,
                                                        const float* __restrict__ b2,
                                                        const float* __restrict__ scale,
                                                        const float* __restrict__ shift,
                                                        float* __restrict__ out) {
  __shared__ float lds[64 * 134];
  const int t = threadIdx.x;
  const int b = blockIdx.x >> 7;
  const int n0 = (blockIdx.x & 127) << 6;
  for (int idx = t; idx < CH * 64; idx += 256) {
    int cc = idx >> 6, nl = idx & 63;
    lds[nl * 134 + cc] = x[((size_t)(b * CH + cc)) * N_PTS + n0 + nl];
  }
  if (t < 64) {
    float4 nv = nrm4[b * N_PTS + n0 + t];
    lds[t * 134 + 128] = nv.x; lds[t * 134 + 129] = nv.y;
    lds[t * 134 + 130] = nv.z; lds[t * 134 + 131] = 0.0f;
  }
  __syncthreads();

  const int og = __builtin_amdgcn_readfirstlane(t >> 6);
  const int nl = t & 63;
  float acc[32];
#pragma unroll
  for (int k = 0; k < 32; ++k) acc[k] = b1[og * 32 + k];
  for (int c2 = 0; c2 < 66; ++c2) {
    float2 xv = *(const float2*)&lds[nl * 134 + 2 * c2];
    const float* wr0 = w1t + (2 * c2) * CH + og * 32;
    const float* wr1 = wr0 + CH;
#pragma unroll
    for (int k = 0; k < 32; ++k) acc[k] = fmaf(wr0[k], xv.x, acc[k]);
#pragma unroll
    for (int k = 0; k < 32; ++k) acc[k] = fmaf(wr1[k], xv.y, acc[k]);
  }
#pragma unroll
  for (int k = 0; k < 32; ++k) {
    float sc = scale[og * 32 + k], sh = shift[og * 32 + k];
    acc[k] = fmaxf(fmaf(acc[k], sc, sh), 0.0f);
  }
  __syncthreads();
#pragma unroll
  for (int k2 = 0; k2 < 16; ++k2)
    *(float2*)&lds[nl * 134 + og * 32 + 2 * k2] = make_float2(acc[2 * k2], acc[2 * k2 + 1]);
  __syncthreads();

  float acc2[32];
#pragma unroll
  for (int k = 0; k < 32; ++k) acc2[k] = b2[og * 32 + k];
  for (int c2 = 0; c2 < 64; ++c2) {
    float2 hv = *(const float2*)&lds[nl * 134 + 2 * c2];
    const float* wr0 = w2t + (2 * c2) * CH + og * 32;
    const float* wr1 = wr0 + CH;
#pragma unroll
    for (int k = 0; k < 32; ++k) acc2[k] = fmaf(wr0[k], hv.x, acc2[k]);
#pragma unroll
    for (int k = 0; k < 32; ++k) acc2[k] = fmaf(wr1[k], hv.y, acc2[k]);
  }
#pragma unroll
  for (int k = 0; k < 32; ++k) {
    int o = og * 32 + k;
    out[((size_t)(b * CH + o)) * N_PTS + n0 + nl] = acc2[k];
  }
}

// ======================================================================
extern "C" void kernel_launch(void* const* d_in, const int* in_sizes, int n_in,
                              void* d_out, int out_size, void* d_ws, size_t ws_size,
                              hipStream_t stream) {
  const float* x     = (const float*)d_in[0];
  const float* xyz   = (const float*)d_in[1];
  const float* w1    = (const float*)d_in[2];
  const float* b1    = (const float*)d_in[3];
  const float* gamma = (const float*)d_in[4];
  const float* beta  = (const float*)d_in[5];
  const float* w2    = (const float*)d_in[6];
  const float* b2    = (const float*)d_in[7];
  float* out = (float*)d_out;

  float* W = (float*)d_ws;
  float4* xyz4 = (float4*)W;                         // 131072 floats
  float4* nrm4 = (float4*)(W + 131072);              // 131072 floats
  float* w1t   = W + 262144;
  float* w2t   = W + 279040;
  float* stats = W + 295424;
  float* scale = W + 295680;
  float* shift = W + 295808;
  unsigned short* nidx = (unsigned short*)(W + 295936);  // 32768*20 u16

  prep_kernel<<<128, 256, 0, stream>>>(xyz, w1, w2, xyz4, w1t, w2t, stats);
  knn_select_kernel<<<BATCH * N_PTS / 64, 512, 0, stream>>>(xyz4, nidx);
  normals_kernel<<<BATCH * N_PTS / 256, 256, 0, stream>>>(xyz4, nidx, nrm4);
  gemm1_stats_kernel<<<BATCH * N_PTS / 64, 256, 0, stream>>>(x, nrm4, w1t, b1, stats, stats + 128);
  bn_finalize_kernel<<<1, 128, 0, stream>>>(stats, stats + 128, gamma, beta, scale, shift);
  fused_out_kernel<<<BATCH * N_PTS / 64, 256, 0, stream>>>(x, nrm4, w1t, b1, w2t, b2, scale, shift, out);
}